// Round 7
// baseline (626.557 us; speedup 1.0000x reference)
//
#include <hip/hip_runtime.h>

#define Nn 10000
#define Ee 160000
#define HID 256
#define EDIM 9
#define INDIM 10
#define Tt 5

typedef _Float16 f16;
typedef _Float16 f16x8 __attribute__((ext_vector_type(8)));
typedef _Float16 f16x4 __attribute__((ext_vector_type(4)));
typedef float f32x4 __attribute__((ext_vector_type(4)));

// ---- mega-prologue: three independent jobs on disjoint block ranges ----
__global__ __launch_bounds__(256) void prologue_kernel(
    const float* __restrict__ edge_attr, const int* __restrict__ dst,
    float* __restrict__ cs, int* __restrict__ deg,
    const float* __restrict__ x, const float* __restrict__ lift_W,
    const float* __restrict__ lift_b, f16* __restrict__ hq,
    const float* __restrict__ Wl, const float* __restrict__ Wr,
    const float* __restrict__ p1, const float* __restrict__ p2,
    const float* __restrict__ bl, const float* __restrict__ br,
    f16* __restrict__ wt, float* __restrict__ biascat) {
  const int blk = blockIdx.x;
  if (blk < 64) {
    float s[9], s2[9];
#pragma unroll
    for (int k = 0; k < 9; ++k) { s[k] = 0.f; s2[k] = 0.f; }
    for (int i = blk * 256 + threadIdx.x; i < Ee; i += 64 * 256) {
#pragma unroll
      for (int k = 0; k < 9; ++k) {
        float v = edge_attr[i * 9 + k];
        s[k] += v; s2[k] += v * v;
      }
    }
#pragma unroll
    for (int k = 0; k < 9; ++k) {
      for (int off = 1; off < 64; off <<= 1) {
        s[k] += __shfl_xor(s[k], off);
        s2[k] += __shfl_xor(s2[k], off);
      }
    }
    if ((threadIdx.x & 63) == 0) {
#pragma unroll
      for (int k = 0; k < 9; ++k) {
        atomicAdd(&cs[k], s[k]);
        atomicAdd(&cs[16 + k], s2[k]);
      }
    }
  } else if (blk < 689) {
    int e = (blk - 64) * 256 + threadIdx.x;
    if (e < Ee) atomicAdd(&deg[dst[e]], 1);
  } else if (blk < 10689) {
    __shared__ float xs[INDIM];
    int n = blk - 689, ch = threadIdx.x;
    if (ch < INDIM) xs[ch] = x[n * INDIM + ch];
    __syncthreads();
    float s = lift_b[ch];
#pragma unroll
    for (int k = 0; k < INDIM; ++k) s += xs[k] * lift_W[k * 256 + ch];
    hq[n * 256 + ch] = (f16)fmaxf(s, 0.f);
  } else {
    int idx = blk - 10689;              // 0..4095
    int nrow = idx & 511, sl = idx >> 9;  // 512 x 8
    int k = threadIdx.x;
    if (sl == 7) {
      int flat = nrow * 256 + k;
      if (flat < 2560) {
        int t = flat >> 9, c = flat & 511;
        biascat[flat] = (c < 256) ? bl[t * 256 + c] : br[t * 256 + c - 256];
      }
      return;
    }
    const float* srcp; int n = nrow; size_t dstoff;
    if (sl < 5) {
      dstoff = (size_t)sl * 131072 + (size_t)nrow * 256 + k;
      if (nrow < 256) srcp = Wl + sl * 65536;
      else { srcp = Wr + sl * 65536; n = nrow - 256; }
    } else {
      if (nrow >= 256) return;
      dstoff = 655360 + (size_t)(sl - 5) * 65536 + (size_t)nrow * 256 + k;
      srcp = (sl == 5) ? p1 : p2;
    }
    wt[dstoff] = (f16)srcp[k * 256 + n];
  }
}

// ---------------- CSR rowptr scan (single block) ----------------
__global__ __launch_bounds__(1024) void scan_kernel(const int* __restrict__ deg,
                                                    int* __restrict__ rowptr,
                                                    int* __restrict__ cursor) {
  __shared__ int part[1024];
  int tid = threadIdx.x;
  const int CH = (Nn + 1023) / 1024;
  int start = tid * CH;
  int s = 0;
  for (int i = 0; i < CH; ++i) { int idx = start + i; if (idx < Nn) s += deg[idx]; }
  part[tid] = s;
  __syncthreads();
  for (int off = 1; off < 1024; off <<= 1) {
    int v = part[tid];
    int w = (tid >= off) ? part[tid - off] : 0;
    __syncthreads();
    part[tid] = v + w;
    __syncthreads();
  }
  int run = part[tid] - s;  // exclusive prefix
  for (int i = 0; i < CH; ++i) {
    int idx = start + i;
    if (idx < Nn) { rowptr[idx] = run; cursor[idx] = run; run += deg[idx]; }
  }
  if (tid == 0) rowptr[Nn] = Ee;
}

// ---- fused CSR fill + src permute + edge-attr normalize (f32, stride 12) ----
__global__ __launch_bounds__(256) void fill_eaperm_kernel(const float* __restrict__ edge_attr,
                                                          const float* __restrict__ cs,
                                                          const int* __restrict__ srcIn,
                                                          const int* __restrict__ dstIn,
                                                          int* __restrict__ cursor,
                                                          int* __restrict__ srcp,
                                                          float* __restrict__ eap) {
  int e = blockIdx.x * 256 + threadIdx.x;
  if (e >= Ee) return;
  int pos = atomicAdd(&cursor[dstIn[e]], 1);
  srcp[pos] = srcIn[e];
  const float* a = edge_attr + e * 9;
  float o[12];
#pragma unroll
  for (int k = 0; k < 9; ++k) {
    float mu = cs[k] * (1.f / Ee);
    float var = fmaxf(cs[16 + k] * (1.f / Ee) - mu * mu, 0.f);
    o[k] = (a[k] - mu) / (sqrtf(var) + 1e-8f);
  }
  o[9] = o[10] = o[11] = 0.f;
  float4 v0 = {o[0], o[1], o[2], o[3]};
  float4 v1 = {o[4], o[5], o[6], o[7]};
  float4 v2 = {o[8], o[9], o[10], o[11]};
  *(float4*)(eap + (size_t)pos * 12 + 0) = v0;
  *(float4*)(eap + (size_t)pos * 12 + 4) = v1;
  *(float4*)(eap + (size_t)pos * 12 + 8) = v2;
}

// ------------- fp16 MFMA GEMM: A staged in LDS, B streamed from L2 -------------
// out2 != nullptr: n-tiles with n0>=256 are routed to out2 at column n0-256.
__global__ __launch_bounds__(256) void gemm16_kernel(const f16* __restrict__ A,
                                                     const f16* __restrict__ BT,
                                                     const float* __restrict__ bias,
                                                     const float* __restrict__ sums,
                                                     const float* __restrict__ gamma,
                                                     const float* __restrict__ beta,
                                                     int act,
                                                     f16* __restrict__ out,
                                                     int M, int OS,
                                                     float* __restrict__ statsout,
                                                     f16* __restrict__ out2) {
  __shared__ __align__(16) f16 As[64][264];
  const int tid = threadIdx.x;
  const int wave = tid >> 6, lane = tid & 63;
  const int l15 = lane & 15, quad = lane >> 4;
  const int m0 = blockIdx.y * 64, n0 = blockIdx.x * 64;
  const int wm = (wave >> 1) * 32, wn = (wave & 1) * 32;
  const int colbase = (tid & 31) * 8;
  float sA[8], tA[8];
  if (act >= 0) {
#pragma unroll
    for (int c4 = 0; c4 < 2; ++c4) {
      float su_[4] = {0.f, 0.f, 0.f, 0.f}, sq_[4] = {0.f, 0.f, 0.f, 0.f};
#pragma unroll
      for (int p = 0; p < 8; ++p) {
        float4 su = *(const float4*)(sums + p * 512 + colbase + c4 * 4);
        float4 sq = *(const float4*)(sums + p * 512 + 256 + colbase + c4 * 4);
        su_[0] += su.x; su_[1] += su.y; su_[2] += su.z; su_[3] += su.w;
        sq_[0] += sq.x; sq_[1] += sq.y; sq_[2] += sq.z; sq_[3] += sq.w;
      }
      float4 g4 = *(const float4*)(gamma + colbase + c4 * 4);
      float4 b4 = *(const float4*)(beta + colbase + c4 * 4);
      float g_[4] = {g4.x, g4.y, g4.z, g4.w};
      float b_[4] = {b4.x, b4.y, b4.z, b4.w};
#pragma unroll
      for (int c = 0; c < 4; ++c) {
        float mu = su_[c] * (1.f / Nn);
        float var = fmaxf(sq_[c] * (1.f / Nn) - mu * mu, 0.f);
        float is = rsqrtf(var + 1e-5f) * g_[c];
        sA[c4 * 4 + c] = is;
        tA[c4 * 4 + c] = b_[c] - mu * is;
      }
    }
  }
  // stage A panel (64x256) only: 8 x 16B chunks per thread
#pragma unroll
  for (int i = 0; i < 8; ++i) {
    int c = tid + 256 * i;
    int row = c >> 5, col = (c & 31) * 8;
    f16x8 av = {};
    int gm = m0 + row;
    if (gm < M) av = *(const f16x8*)(A + (size_t)gm * 256 + col);
    if (act >= 0) {
#pragma unroll
      for (int e = 0; e < 8; ++e) {
        float y = (float)av[e] * sA[e] + tA[e];
        if (act == 0) y = y > 0.f ? y : (__expf(y) - 1.f);
        else y = fmaxf(y, 0.f);
        av[e] = (f16)y;
      }
    }
    *(f16x8*)(&As[row][col]) = av;
  }
  __syncthreads();
  const f16* pb0 = BT + (size_t)(n0 + wn + l15) * 256 + quad * 8;
  const f16* pb1 = BT + (size_t)(n0 + wn + 16 + l15) * 256 + quad * 8;
  f32x4 zero4 = {0.f, 0.f, 0.f, 0.f};
  f32x4 acc[2][2] = {{zero4, zero4}, {zero4, zero4}};
#pragma unroll
  for (int kk = 0; kk < 256; kk += 32) {
    f16x8 a0 = *(const f16x8*)(&As[wm + l15][kk + quad * 8]);
    f16x8 a1 = *(const f16x8*)(&As[wm + 16 + l15][kk + quad * 8]);
    f16x8 b0 = *(const f16x8*)(pb0 + kk);
    f16x8 b1 = *(const f16x8*)(pb1 + kk);
    acc[0][0] = __builtin_amdgcn_mfma_f32_16x16x32_f16(a0, b0, acc[0][0], 0, 0, 0);
    acc[0][1] = __builtin_amdgcn_mfma_f32_16x16x32_f16(a0, b1, acc[0][1], 0, 0, 0);
    acc[1][0] = __builtin_amdgcn_mfma_f32_16x16x32_f16(a1, b0, acc[1][0], 0, 0, 0);
    acc[1][1] = __builtin_amdgcn_mfma_f32_16x16x32_f16(a1, b1, acc[1][1], 0, 0, 0);
  }
  // epilogue: bias add, fp16 via LDS transpose; optional register-space stats
  __syncthreads();
  f16* Cs = (f16*)&As[0][0];  // 64 x 72 tile (reuses As)
  float st_s[2] = {0.f, 0.f}, st_q[2] = {0.f, 0.f};
#pragma unroll
  for (int ni = 0; ni < 2; ++ni) {
    int nl = wn + ni * 16 + l15;
    float bv = bias[n0 + nl];
#pragma unroll
    for (int mi = 0; mi < 2; ++mi)
#pragma unroll
      for (int r = 0; r < 4; ++r) {
        f16 hv = (f16)(acc[mi][ni][r] + bv);
        Cs[(wm + mi * 16 + quad * 4 + r) * 72 + nl] = hv;
        if (statsout) {
          int gm = m0 + wm + mi * 16 + quad * 4 + r;
          float xv = (gm < M) ? (float)hv : 0.f;
          st_s[ni] += xv;
          st_q[ni] += xv * xv;
        }
      }
  }
  if (statsout) {
    float* bp = statsout + (blockIdx.y & 7) * 512;
#pragma unroll
    for (int ni = 0; ni < 2; ++ni) {
      float s = st_s[ni], q = st_q[ni];
      s += __shfl_xor(s, 16); q += __shfl_xor(q, 16);
      s += __shfl_xor(s, 32); q += __shfl_xor(q, 32);
      if (quad == 0) {
        int col = n0 + wn + ni * 16 + l15;
        atomicAdd(&bp[col], s);
        atomicAdd(&bp[256 + col], q);
      }
    }
  }
  __syncthreads();
  {
    int row = tid >> 2, c4 = (tid & 3) * 16;
    int gm = m0 + row;
    f16* op = out; int nc = n0;
    if (out2 && n0 >= 256) { op = out2; nc = n0 - 256; }
    if (gm < M) {
      f16x8 v0 = *(const f16x8*)(&Cs[row * 72 + c4]);
      f16x8 v1 = *(const f16x8*)(&Cs[row * 72 + c4 + 8]);
      *(f16x8*)(op + (size_t)gm * OS + nc + c4) = v0;
      *(f16x8*)(op + (size_t)gm * OS + nc + c4 + 8) = v1;
    }
  }
}

// ---- Fused GATv2 + BN stats: wave/node, batch-4, srcp register-prefetch ----
// R1-R6 model: VALU-busy ~22us invariant; stall ~25us is the 2-hop dependent
// chain {srcp load -> xlb gather} per batch. Fix: prefetch the node's whole
// src list (<=~40 contiguous ints) into one register via a single wave-wide
// load at wave start; per-batch js comes from __shfl(sreg, off) (wave-uniform
// off, few cycles) -> load #1 removed from every iteration's critical path.
// Bit-identical arithmetic (same js values, same order). Degree>64 guarded by
// never-taken (Poisson-16) fallback to the direct load.
__global__ __launch_bounds__(256) void gat_fused(const f16* __restrict__ xlb,
                                                 const f16* __restrict__ xrb,
                                                 const float* __restrict__ eap,
                                                 const int* __restrict__ srcp,
                                                 const int* __restrict__ rowptr,
                                                 const float* __restrict__ We_t,
                                                 const float* __restrict__ att_t,
                                                 const float* __restrict__ cb_t,
                                                 f16* __restrict__ outb,
                                                 float* __restrict__ bns) {
  __shared__ float ls[2048];  // [wave][sum 256 | sumsq 256]
  int wave = threadIdx.x >> 6, lane = threadIdx.x & 63;
  int i = blockIdx.x * 4 + wave;  // 2500 * 4 == Nn exactly
  int ch = lane * 4;  // lane owns flat channels [ch, ch+4); head = lane>>3
  float we[9][4];
#pragma unroll
  for (int k = 0; k < 9; ++k) {
    float4 w4 = *(const float4*)(We_t + k * 256 + ch);
    we[k][0] = w4.x; we[k][1] = w4.y; we[k][2] = w4.z; we[k][3] = w4.w;
  }
  float4 a4 = *(const float4*)(att_t + ch);
  float att[4] = {a4.x, a4.y, a4.z, a4.w};
  f16x4 xr4 = *(const f16x4*)(xrb + (size_t)i * 256 + ch);
  float xri[4] = {(float)xr4[0], (float)xr4[1], (float)xr4[2], (float)xr4[3]};
  float acc[4] = {0.f, 0.f, 0.f, 0.f};
  float d = 0.f;
  int r0 = rowptr[i], r1 = rowptr[i + 1];
  int deg = r1 - r0;
  int sreg = 0;
  if (deg > 0) {
    int sidx = r0 + lane;
    if (sidx > r1 - 1) sidx = r1 - 1;
    sreg = srcp[sidx];  // one wave-wide load covers the whole src list
  }
  for (int base = r0; base < r1; base += 4) {
    int cnt = r1 - base;  // >= 1
    int ib[4];
#pragma unroll
    for (int b = 0; b < 4; ++b) ib[b] = base + (b < cnt ? b : cnt - 1);
    int js[4];
#pragma unroll
    for (int b = 0; b < 4; ++b) {
      int off = ib[b] - r0;  // wave-uniform
      js[b] = (off < 64) ? __shfl(sreg, off) : srcp[ib[b]];
    }
    float xlv[4][4];
#pragma unroll
    for (int b = 0; b < 4; ++b) {
      f16x4 v4 = *(const f16x4*)(xlb + (size_t)js[b] * 256 + ch);
      xlv[b][0] = (float)v4[0]; xlv[b][1] = (float)v4[1];
      xlv[b][2] = (float)v4[2]; xlv[b][3] = (float)v4[3];
    }
    float sp[4];
#pragma unroll
    for (int b = 0; b < 4; ++b) {
      const float* ep = eap + (size_t)ib[b] * 12;
      float4 e0 = *(const float4*)ep;
      float4 e1 = *(const float4*)(ep + 4);
      float e8 = ep[8];
      float s = 0.f;
#pragma unroll
      for (int c = 0; c < 4; ++c) {
        float v = xlv[b][c] + xri[c];
        v += e0.x * we[0][c] + e0.y * we[1][c] + e0.z * we[2][c] + e0.w * we[3][c];
        v += e1.x * we[4][c] + e1.y * we[5][c] + e1.z * we[6][c] + e1.w * we[7][c];
        v += e8 * we[8][c];
        v = v > 0.f ? v : 0.2f * v;  // leaky_relu 0.2
        s += att[c] * v;
      }
      sp[b] = s;
    }
#pragma unroll
    for (int b = 0; b < 4; ++b) {
      sp[b] += __shfl_xor(sp[b], 1);
      sp[b] += __shfl_xor(sp[b], 2);
      sp[b] += __shfl_xor(sp[b], 4);
    }
#pragma unroll
    for (int b = 0; b < 4; ++b) {
      float z = (b < cnt) ? __expf(fminf(sp[b], 75.f)) : 0.f;
      d += z;
#pragma unroll
      for (int c = 0; c < 4; ++c) acc[c] += z * xlv[b][c];
    }
  }
  float inv = 1.f / (d + 1e-16f);  // empty node -> bias only (matches ref)
  float4 cb4 = *(const float4*)(cb_t + ch);
  f16x4 o;
  o[0] = (f16)(acc[0] * inv + cb4.x);
  o[1] = (f16)(acc[1] * inv + cb4.y);
  o[2] = (f16)(acc[2] * inv + cb4.z);
  o[3] = (f16)(acc[3] * inv + cb4.w);
  *(f16x4*)(outb + (size_t)i * 256 + ch) = o;
  // fused BN stats on the f16-rounded output
#pragma unroll
  for (int c = 0; c < 4; ++c) {
    float xv = (float)o[c];
    ls[wave * 512 + ch + c] = xv;
    ls[wave * 512 + 256 + ch + c] = xv * xv;
  }
  __syncthreads();
  float* bp = bns + (blockIdx.x & 7) * 512;  // 8-way partials: contention /8
  for (int q = threadIdx.x; q < 512; q += 256) {
    float sv = ls[q] + ls[512 + q] + ls[1024 + q] + ls[1536 + q];
    atomicAdd(&bp[q], sv);
  }
}

// ---------------- final: BN(pbn2)+ReLU folded, 256 -> 3 projection ----------------
__global__ __launch_bounds__(256) void final_kernel(const f16* __restrict__ hq,
                                                    const float* __restrict__ sums,
                                                    const float* __restrict__ gamma,
                                                    const float* __restrict__ beta,
                                                    const float* __restrict__ W,
                                                    const float* __restrict__ b,
                                                    float* __restrict__ out3) {
  int wave = threadIdx.x >> 6, lane = threadIdx.x & 63;
  int n = blockIdx.x * 4 + wave;
  if (n >= Nn) return;
  int ch = lane * 4;
  float su_[4] = {0.f, 0.f, 0.f, 0.f}, sq_[4] = {0.f, 0.f, 0.f, 0.f};
#pragma unroll
  for (int p = 0; p < 8; ++p) {
    float4 su = *(const float4*)(sums + p * 512 + ch);
    float4 sq = *(const float4*)(sums + p * 512 + 256 + ch);
    su_[0] += su.x; su_[1] += su.y; su_[2] += su.z; su_[3] += su.w;
    sq_[0] += sq.x; sq_[1] += sq.y; sq_[2] += sq.z; sq_[3] += sq.w;
  }
  float4 g4 = *(const float4*)(gamma + ch);
  float4 b4 = *(const float4*)(beta + ch);
  float g_[4] = {g4.x, g4.y, g4.z, g4.w};
  float bb_[4] = {b4.x, b4.y, b4.z, b4.w};
  f16x4 h4 = *(const f16x4*)(hq + (size_t)n * 256 + ch);
  float s0 = 0.f, s1 = 0.f, s2 = 0.f;
#pragma unroll
  for (int c = 0; c < 4; ++c) {
    float mu = su_[c] * (1.f / Nn);
    float var = fmaxf(sq_[c] * (1.f / Nn) - mu * mu, 0.f);
    float is = rsqrtf(var + 1e-5f) * g_[c];
    float y = fmaxf(((float)h4[c] - mu) * is + bb_[c], 0.f);
    const float* w = W + (ch + c) * 3;
    s0 += y * w[0]; s1 += y * w[1]; s2 += y * w[2];
  }
  for (int off = 1; off < 64; off <<= 1) {
    s0 += __shfl_xor(s0, off);
    s1 += __shfl_xor(s1, off);
    s2 += __shfl_xor(s2, off);
  }
  if (lane == 0) {
    out3[n * 3 + 0] = s0 + b[0];
    out3[n * 3 + 1] = s1 + b[1];
    out3[n * 3 + 2] = s2 + b[2];
  }
}

extern "C" void kernel_launch(void* const* d_in, const int* in_sizes, int n_in,
                              void* d_out, int out_size, void* d_ws, size_t ws_size,
                              hipStream_t stream) {
  const float* x         = (const float*)d_in[0];
  const float* edge_attr = (const float*)d_in[1];
  const int*   eidx      = (const int*)d_in[2];
  const float* lift_W    = (const float*)d_in[3];
  const float* lift_b    = (const float*)d_in[4];
  const float* Wl        = (const float*)d_in[5];
  const float* bl        = (const float*)d_in[6];
  const float* Wr        = (const float*)d_in[7];
  const float* br        = (const float*)d_in[8];
  const float* We        = (const float*)d_in[9];
  const float* att       = (const float*)d_in[10];
  const float* conv_b    = (const float*)d_in[11];
  const float* bn_g      = (const float*)d_in[12];
  const float* bn_b      = (const float*)d_in[13];
  const float* p1_W      = (const float*)d_in[14];
  const float* p1_b      = (const float*)d_in[15];
  const float* pbn1_g    = (const float*)d_in[16];
  const float* pbn1_b    = (const float*)d_in[17];
  const float* p2_W      = (const float*)d_in[18];
  const float* p2_b      = (const float*)d_in[19];
  const float* pbn2_g    = (const float*)d_in[20];
  const float* pbn2_b    = (const float*)d_in[21];
  const float* p3_W      = (const float*)d_in[22];
  const float* p3_b      = (const float*)d_in[23];
  const int* srcI = eidx;
  const int* dstI = eidx + Ee;

  char* wp = (char*)d_ws;
  auto carve = [&](size_t bytes) -> void* {
    void* p = (void*)wp;
    wp += (bytes + 255) & ~(size_t)255;
    return p;
  };
  // zero region: cstats(32) + bnsA(7 sets x 8 partials x 512) + deg(Nn)
  char*  zr     = (char*)carve((size_t)(32 + 7 * 4096 + Nn) * 4);
  float* cstats = (float*)zr;
  float* bnsA   = (float*)(zr + 32 * 4);
  int*   deg    = (int*)(zr + (32 + 7 * 4096) * 4);
  float* eap    = (float*)carve((size_t)Ee * 12 * sizeof(float));
  f16*   h16    = (f16*)carve((size_t)Nn * 256 * sizeof(f16));
  f16*   w16t   = (f16*)carve((size_t)786432 * sizeof(f16));
  float* biascat= (float*)carve((size_t)2560 * sizeof(float));
  f16*   xlb    = (f16*)carve((size_t)Nn * 256 * sizeof(f16));
  f16*   xrb    = (f16*)carve((size_t)Nn * 256 * sizeof(f16));
  f16*   outb16 = (f16*)carve((size_t)Nn * 256 * sizeof(f16));
  int*   rowptr = (int*)carve((size_t)(Nn + 1) * sizeof(int));
  int*   cursor = (int*)carve((size_t)Nn * sizeof(int));
  int*   srcp   = (int*)carve((size_t)Ee * sizeof(int));

  hipMemsetAsync(zr, 0, (size_t)(32 + 7 * 4096 + Nn) * 4, stream);

  prologue_kernel<<<14785, 256, 0, stream>>>(edge_attr, dstI, cstats, deg,
                                             x, lift_W, lift_b, h16,
                                             Wl, Wr, p1_W, p2_W, bl, br, w16t, biascat);
  scan_kernel<<<1, 1024, 0, stream>>>(deg, rowptr, cursor);
  fill_eaperm_kernel<<<(Ee + 255) / 256, 256, 0, stream>>>(edge_attr, cstats, srcI, dstI,
                                                           cursor, srcp, eap);

  const int MB = (Nn + 63) / 64;  // 157
  for (int t = 0; t < Tt; ++t) {
    const f16* Ain = (t == 0) ? h16 : outb16;
    const float* sums = (t == 0) ? nullptr : bnsA + (size_t)(t - 1) * 4096;
    int act = (t == 0) ? -1 : 0;
    gemm16_kernel<<<dim3(8, MB), 256, 0, stream>>>(Ain, w16t + (size_t)t * 131072,
                                                   biascat + t * 512, sums,
                                                   bn_g + (t > 0 ? (t - 1) * 256 : 0),
                                                   bn_b + (t > 0 ? (t - 1) * 256 : 0),
                                                   act, xlb, Nn, 256, nullptr, xrb);
    gat_fused<<<2500, 256, 0, stream>>>(xlb, xrb, eap, srcp, rowptr,
                                        We + t * 9 * 256, att + t * 256,
                                        conv_b + t * 256, outb16,
                                        bnsA + (size_t)t * 4096);
  }
  // projection head: BN folds in A-staging; output stats fused in gemm epilogue
  f16* pA = xlb;  // Nn*256, reused
  f16* pB = xrb;  // Nn*256, reused
  gemm16_kernel<<<dim3(4, MB), 256, 0, stream>>>(outb16, w16t + 655360, p1_b,
                                                 bnsA + 4 * 4096, bn_g + 4 * 256, bn_b + 4 * 256,
                                                 0, pA, Nn, 256, bnsA + 5 * 4096, nullptr);
  gemm16_kernel<<<dim3(4, MB), 256, 0, stream>>>(pA, w16t + 720896, p2_b,
                                                 bnsA + 5 * 4096, pbn1_g, pbn1_b,
                                                 1, pB, Nn, 256, bnsA + 6 * 4096, nullptr);
  final_kernel<<<2500, 256, 0, stream>>>(pB, bnsA + 6 * 4096, pbn2_g, pbn2_b, p3_W, p3_b,
                                         (float*)d_out);
}

// Round 8
// 580.956 us; speedup vs baseline: 1.0785x; 1.0785x over previous
//
#include <hip/hip_runtime.h>

#define Nn 10000
#define Ee 160000
#define HID 256
#define EDIM 9
#define INDIM 10
#define Tt 5

typedef _Float16 f16;
typedef _Float16 f16x8 __attribute__((ext_vector_type(8)));
typedef _Float16 f16x4 __attribute__((ext_vector_type(4)));
typedef float f32x4 __attribute__((ext_vector_type(4)));

// ---- mega-prologue: independent jobs on disjoint block ranges ----
// blocks [0,64):        edge-attr column stats
// blocks [64,689):      degree histogram
// blocks [689,10689):   lift  h = relu(x @ lift_W + b) -> f16
// blocks [10689,10881): weight fp32->f16 transpose, LDS-tiled 64x64 (coalesced;
//                       old per-row version read stride-1KB = 16x line traffic)
// block  10881:         bias concat
__global__ __launch_bounds__(256) void prologue_kernel(
    const float* __restrict__ edge_attr, const int* __restrict__ dst,
    float* __restrict__ cs, int* __restrict__ deg,
    const float* __restrict__ x, const float* __restrict__ lift_W,
    const float* __restrict__ lift_b, f16* __restrict__ hq,
    const float* __restrict__ Wl, const float* __restrict__ Wr,
    const float* __restrict__ p1, const float* __restrict__ p2,
    const float* __restrict__ bl, const float* __restrict__ br,
    f16* __restrict__ wt, float* __restrict__ biascat) {
  __shared__ float tile[64][65];
  const int blk = blockIdx.x;
  if (blk < 64) {
    float s[9], s2[9];
#pragma unroll
    for (int k = 0; k < 9; ++k) { s[k] = 0.f; s2[k] = 0.f; }
    for (int i = blk * 256 + threadIdx.x; i < Ee; i += 64 * 256) {
#pragma unroll
      for (int k = 0; k < 9; ++k) {
        float v = edge_attr[i * 9 + k];
        s[k] += v; s2[k] += v * v;
      }
    }
#pragma unroll
    for (int k = 0; k < 9; ++k) {
      for (int off = 1; off < 64; off <<= 1) {
        s[k] += __shfl_xor(s[k], off);
        s2[k] += __shfl_xor(s2[k], off);
      }
    }
    if ((threadIdx.x & 63) == 0) {
#pragma unroll
      for (int k = 0; k < 9; ++k) {
        atomicAdd(&cs[k], s[k]);
        atomicAdd(&cs[16 + k], s2[k]);
      }
    }
  } else if (blk < 689) {
    int e = (blk - 64) * 256 + threadIdx.x;
    if (e < Ee) atomicAdd(&deg[dst[e]], 1);
  } else if (blk < 10689) {
    __shared__ float xs[INDIM];
    int n = blk - 689, ch = threadIdx.x;
    if (ch < INDIM) xs[ch] = x[n * INDIM + ch];
    __syncthreads();
    float s = lift_b[ch];
#pragma unroll
    for (int k = 0; k < INDIM; ++k) s += xs[k] * lift_W[k * 256 + ch];
    hq[n * 256 + ch] = (f16)fmaxf(s, 0.f);
  } else if (blk < 10881) {
    // coalesced transpose: src fp32 [256 k][256 n] -> wt f16 [n][k]
    int b = blk - 10689;            // 0..191
    int m = b >> 4, t4 = b & 15;    // matrix, 64x64 tile
    int ti = t4 >> 2, tj = t4 & 3;  // out-row (n) tile, k tile
    const float* src; size_t dbase;
    if (m < 10) {
      int t = m >> 1;
      src = (m & 1) ? (Wr + t * 65536) : (Wl + t * 65536);
      dbase = (size_t)t * 131072 + ((m & 1) ? (size_t)65536 : 0);
    } else if (m == 10) { src = p1; dbase = 655360; }
    else { src = p2; dbase = 720896; }
#pragma unroll
    for (int p = 0; p < 16; ++p) {
      int idx = threadIdx.x + p * 256;  // 0..4095
      int kl = idx >> 6, nl = idx & 63;
      tile[kl][nl] = src[(size_t)(tj * 64 + kl) * 256 + ti * 64 + nl];
    }
    __syncthreads();
#pragma unroll
    for (int p = 0; p < 16; ++p) {
      int idx = threadIdx.x + p * 256;
      int nl = idx >> 6, kl = idx & 63;
      wt[dbase + (size_t)(ti * 64 + nl) * 256 + tj * 64 + kl] = (f16)tile[kl][nl];
    }
  } else {
    for (int flat = threadIdx.x; flat < 2560; flat += 256) {
      int t = flat >> 9, c = flat & 511;
      biascat[flat] = (c < 256) ? bl[t * 256 + c] : br[t * 256 + c - 256];
    }
  }
}

// ---------------- CSR rowptr scan (single block) ----------------
__global__ __launch_bounds__(1024) void scan_kernel(const int* __restrict__ deg,
                                                    int* __restrict__ rowptr,
                                                    int* __restrict__ cursor) {
  __shared__ int part[1024];
  int tid = threadIdx.x;
  const int CH = (Nn + 1023) / 1024;
  int start = tid * CH;
  int s = 0;
  for (int i = 0; i < CH; ++i) { int idx = start + i; if (idx < Nn) s += deg[idx]; }
  part[tid] = s;
  __syncthreads();
  for (int off = 1; off < 1024; off <<= 1) {
    int v = part[tid];
    int w = (tid >= off) ? part[tid - off] : 0;
    __syncthreads();
    part[tid] = v + w;
    __syncthreads();
  }
  int run = part[tid] - s;  // exclusive prefix
  for (int i = 0; i < CH; ++i) {
    int idx = start + i;
    if (idx < Nn) { rowptr[idx] = run; cursor[idx] = run; run += deg[idx]; }
  }
  if (tid == 0) rowptr[Nn] = Ee;
}

// ---- fused CSR fill + src permute + edge-attr normalize (f32, stride 12) ----
__global__ __launch_bounds__(256) void fill_eaperm_kernel(const float* __restrict__ edge_attr,
                                                          const float* __restrict__ cs,
                                                          const int* __restrict__ srcIn,
                                                          const int* __restrict__ dstIn,
                                                          int* __restrict__ cursor,
                                                          int* __restrict__ srcp,
                                                          float* __restrict__ eap) {
  int e = blockIdx.x * 256 + threadIdx.x;
  if (e >= Ee) return;
  int pos = atomicAdd(&cursor[dstIn[e]], 1);
  srcp[pos] = srcIn[e];
  const float* a = edge_attr + e * 9;
  float o[12];
#pragma unroll
  for (int k = 0; k < 9; ++k) {
    float mu = cs[k] * (1.f / Ee);
    float var = fmaxf(cs[16 + k] * (1.f / Ee) - mu * mu, 0.f);
    o[k] = (a[k] - mu) / (sqrtf(var) + 1e-8f);
  }
  o[9] = o[10] = o[11] = 0.f;
  float4 v0 = {o[0], o[1], o[2], o[3]};
  float4 v1 = {o[4], o[5], o[6], o[7]};
  float4 v2 = {o[8], o[9], o[10], o[11]};
  *(float4*)(eap + (size_t)pos * 12 + 0) = v0;
  *(float4*)(eap + (size_t)pos * 12 + 4) = v1;
  *(float4*)(eap + (size_t)pos * 12 + 8) = v2;
}

// ------------- fp16 MFMA GEMM: A staged in LDS, B streamed from L2 -------------
// out2 != nullptr: n-tiles with n0>=256 are routed to out2 at column n0-256.
__global__ __launch_bounds__(256) void gemm16_kernel(const f16* __restrict__ A,
                                                     const f16* __restrict__ BT,
                                                     const float* __restrict__ bias,
                                                     const float* __restrict__ sums,
                                                     const float* __restrict__ gamma,
                                                     const float* __restrict__ beta,
                                                     int act,
                                                     f16* __restrict__ out,
                                                     int M, int OS,
                                                     float* __restrict__ statsout,
                                                     f16* __restrict__ out2) {
  __shared__ __align__(16) f16 As[64][264];
  const int tid = threadIdx.x;
  const int wave = tid >> 6, lane = tid & 63;
  const int l15 = lane & 15, quad = lane >> 4;
  const int m0 = blockIdx.y * 64, n0 = blockIdx.x * 64;
  const int wm = (wave >> 1) * 32, wn = (wave & 1) * 32;
  const int colbase = (tid & 31) * 8;
  float sA[8], tA[8];
  if (act >= 0) {
#pragma unroll
    for (int c4 = 0; c4 < 2; ++c4) {
      float su_[4] = {0.f, 0.f, 0.f, 0.f}, sq_[4] = {0.f, 0.f, 0.f, 0.f};
#pragma unroll
      for (int p = 0; p < 8; ++p) {
        float4 su = *(const float4*)(sums + p * 512 + colbase + c4 * 4);
        float4 sq = *(const float4*)(sums + p * 512 + 256 + colbase + c4 * 4);
        su_[0] += su.x; su_[1] += su.y; su_[2] += su.z; su_[3] += su.w;
        sq_[0] += sq.x; sq_[1] += sq.y; sq_[2] += sq.z; sq_[3] += sq.w;
      }
      float4 g4 = *(const float4*)(gamma + colbase + c4 * 4);
      float4 b4 = *(const float4*)(beta + colbase + c4 * 4);
      float g_[4] = {g4.x, g4.y, g4.z, g4.w};
      float b_[4] = {b4.x, b4.y, b4.z, b4.w};
#pragma unroll
      for (int c = 0; c < 4; ++c) {
        float mu = su_[c] * (1.f / Nn);
        float var = fmaxf(sq_[c] * (1.f / Nn) - mu * mu, 0.f);
        float is = rsqrtf(var + 1e-5f) * g_[c];
        sA[c4 * 4 + c] = is;
        tA[c4 * 4 + c] = b_[c] - mu * is;
      }
    }
  }
  // stage A panel (64x256) only: 8 x 16B chunks per thread
#pragma unroll
  for (int i = 0; i < 8; ++i) {
    int c = tid + 256 * i;
    int row = c >> 5, col = (c & 31) * 8;
    f16x8 av = {};
    int gm = m0 + row;
    if (gm < M) av = *(const f16x8*)(A + (size_t)gm * 256 + col);
    if (act >= 0) {
#pragma unroll
      for (int e = 0; e < 8; ++e) {
        float y = (float)av[e] * sA[e] + tA[e];
        if (act == 0) y = y > 0.f ? y : (__expf(y) - 1.f);
        else y = fmaxf(y, 0.f);
        av[e] = (f16)y;
      }
    }
    *(f16x8*)(&As[row][col]) = av;
  }
  __syncthreads();
  const f16* pb0 = BT + (size_t)(n0 + wn + l15) * 256 + quad * 8;
  const f16* pb1 = BT + (size_t)(n0 + wn + 16 + l15) * 256 + quad * 8;
  f32x4 zero4 = {0.f, 0.f, 0.f, 0.f};
  f32x4 acc[2][2] = {{zero4, zero4}, {zero4, zero4}};
#pragma unroll
  for (int kk = 0; kk < 256; kk += 32) {
    f16x8 a0 = *(const f16x8*)(&As[wm + l15][kk + quad * 8]);
    f16x8 a1 = *(const f16x8*)(&As[wm + 16 + l15][kk + quad * 8]);
    f16x8 b0 = *(const f16x8*)(pb0 + kk);
    f16x8 b1 = *(const f16x8*)(pb1 + kk);
    acc[0][0] = __builtin_amdgcn_mfma_f32_16x16x32_f16(a0, b0, acc[0][0], 0, 0, 0);
    acc[0][1] = __builtin_amdgcn_mfma_f32_16x16x32_f16(a0, b1, acc[0][1], 0, 0, 0);
    acc[1][0] = __builtin_amdgcn_mfma_f32_16x16x32_f16(a1, b0, acc[1][0], 0, 0, 0);
    acc[1][1] = __builtin_amdgcn_mfma_f32_16x16x32_f16(a1, b1, acc[1][1], 0, 0, 0);
  }
  // epilogue: bias add, fp16 via LDS transpose; optional register-space stats
  __syncthreads();
  f16* Cs = (f16*)&As[0][0];  // 64 x 72 tile (reuses As)
  float st_s[2] = {0.f, 0.f}, st_q[2] = {0.f, 0.f};
#pragma unroll
  for (int ni = 0; ni < 2; ++ni) {
    int nl = wn + ni * 16 + l15;
    float bv = bias[n0 + nl];
#pragma unroll
    for (int mi = 0; mi < 2; ++mi)
#pragma unroll
      for (int r = 0; r < 4; ++r) {
        f16 hv = (f16)(acc[mi][ni][r] + bv);
        Cs[(wm + mi * 16 + quad * 4 + r) * 72 + nl] = hv;
        if (statsout) {
          int gm = m0 + wm + mi * 16 + quad * 4 + r;
          float xv = (gm < M) ? (float)hv : 0.f;
          st_s[ni] += xv;
          st_q[ni] += xv * xv;
        }
      }
  }
  if (statsout) {
    float* bp = statsout + (blockIdx.y & 7) * 512;
#pragma unroll
    for (int ni = 0; ni < 2; ++ni) {
      float s = st_s[ni], q = st_q[ni];
      s += __shfl_xor(s, 16); q += __shfl_xor(q, 16);
      s += __shfl_xor(s, 32); q += __shfl_xor(q, 32);
      if (quad == 0) {
        int col = n0 + wn + ni * 16 + l15;
        atomicAdd(&bp[col], s);
        atomicAdd(&bp[256 + col], q);
      }
    }
  }
  __syncthreads();
  {
    int row = tid >> 2, c4 = (tid & 3) * 16;
    int gm = m0 + row;
    f16* op = out; int nc = n0;
    if (out2 && n0 >= 256) { op = out2; nc = n0 - 256; }
    if (gm < M) {
      f16x8 v0 = *(const f16x8*)(&Cs[row * 72 + c4]);
      f16x8 v1 = *(const f16x8*)(&Cs[row * 72 + c4 + 8]);
      *(f16x8*)(op + (size_t)gm * OS + nc + c4) = v0;
      *(f16x8*)(op + (size_t)gm * OS + nc + c4 + 8) = v1;
    }
  }
}

// ---- Fused GATv2 + BN stats: wave/node, batch-4 (verified R6 body) ----
// R7 lesson: srcp-prefetch-via-shfl put ds_bpermute ON the gather dependency
// chain -> reverted. This round's only gat change: eap loads are NON-TEMPORAL
// (evict-first). eap streams 7.7 MB/dispatch with zero intra-dispatch reuse and
// was thrashing the 5.1 MB xlb gather working set out of L2; nt keeps xlb
// resident -> higher gather hit rate. Bit-identical values.
__global__ __launch_bounds__(256) void gat_fused(const f16* __restrict__ xlb,
                                                 const f16* __restrict__ xrb,
                                                 const float* __restrict__ eap,
                                                 const int* __restrict__ srcp,
                                                 const int* __restrict__ rowptr,
                                                 const float* __restrict__ We_t,
                                                 const float* __restrict__ att_t,
                                                 const float* __restrict__ cb_t,
                                                 f16* __restrict__ outb,
                                                 float* __restrict__ bns) {
  __shared__ float ls[2048];  // [wave][sum 256 | sumsq 256]
  int wave = threadIdx.x >> 6, lane = threadIdx.x & 63;
  int i = blockIdx.x * 4 + wave;  // 2500 * 4 == Nn exactly
  int ch = lane * 4;  // lane owns flat channels [ch, ch+4); head = lane>>3
  float we[9][4];
#pragma unroll
  for (int k = 0; k < 9; ++k) {
    float4 w4 = *(const float4*)(We_t + k * 256 + ch);
    we[k][0] = w4.x; we[k][1] = w4.y; we[k][2] = w4.z; we[k][3] = w4.w;
  }
  float4 a4 = *(const float4*)(att_t + ch);
  float att[4] = {a4.x, a4.y, a4.z, a4.w};
  f16x4 xr4 = *(const f16x4*)(xrb + (size_t)i * 256 + ch);
  float xri[4] = {(float)xr4[0], (float)xr4[1], (float)xr4[2], (float)xr4[3]};
  float acc[4] = {0.f, 0.f, 0.f, 0.f};
  float d = 0.f;
  int r0 = rowptr[i], r1 = rowptr[i + 1];
  for (int base = r0; base < r1; base += 4) {
    int cnt = r1 - base;  // >= 1
    int ib[4];
#pragma unroll
    for (int b = 0; b < 4; ++b) ib[b] = base + (b < cnt ? b : cnt - 1);
    int js[4];
#pragma unroll
    for (int b = 0; b < 4; ++b) js[b] = srcp[ib[b]];
    float xlv[4][4];
#pragma unroll
    for (int b = 0; b < 4; ++b) {
      f16x4 v4 = *(const f16x4*)(xlb + (size_t)js[b] * 256 + ch);
      xlv[b][0] = (float)v4[0]; xlv[b][1] = (float)v4[1];
      xlv[b][2] = (float)v4[2]; xlv[b][3] = (float)v4[3];
    }
    float sp[4];
#pragma unroll
    for (int b = 0; b < 4; ++b) {
      const float* ep = eap + (size_t)ib[b] * 12;
      f32x4 e0 = __builtin_nontemporal_load((const f32x4*)ep);
      f32x4 e1 = __builtin_nontemporal_load((const f32x4*)(ep + 4));
      float e8 = __builtin_nontemporal_load(ep + 8);
      float s = 0.f;
#pragma unroll
      for (int c = 0; c < 4; ++c) {
        float v = xlv[b][c] + xri[c];
        v += e0[0] * we[0][c] + e0[1] * we[1][c] + e0[2] * we[2][c] + e0[3] * we[3][c];
        v += e1[0] * we[4][c] + e1[1] * we[5][c] + e1[2] * we[6][c] + e1[3] * we[7][c];
        v += e8 * we[8][c];
        v = v > 0.f ? v : 0.2f * v;  // leaky_relu 0.2
        s += att[c] * v;
      }
      sp[b] = s;
    }
#pragma unroll
    for (int b = 0; b < 4; ++b) {
      sp[b] += __shfl_xor(sp[b], 1);
      sp[b] += __shfl_xor(sp[b], 2);
      sp[b] += __shfl_xor(sp[b], 4);
    }
#pragma unroll
    for (int b = 0; b < 4; ++b) {
      float z = (b < cnt) ? __expf(fminf(sp[b], 75.f)) : 0.f;
      d += z;
#pragma unroll
      for (int c = 0; c < 4; ++c) acc[c] += z * xlv[b][c];
    }
  }
  float inv = 1.f / (d + 1e-16f);  // empty node -> bias only (matches ref)
  float4 cb4 = *(const float4*)(cb_t + ch);
  f16x4 o;
  o[0] = (f16)(acc[0] * inv + cb4.x);
  o[1] = (f16)(acc[1] * inv + cb4.y);
  o[2] = (f16)(acc[2] * inv + cb4.z);
  o[3] = (f16)(acc[3] * inv + cb4.w);
  *(f16x4*)(outb + (size_t)i * 256 + ch) = o;
  // fused BN stats on the f16-rounded output
#pragma unroll
  for (int c = 0; c < 4; ++c) {
    float xv = (float)o[c];
    ls[wave * 512 + ch + c] = xv;
    ls[wave * 512 + 256 + ch + c] = xv * xv;
  }
  __syncthreads();
  float* bp = bns + (blockIdx.x & 7) * 512;  // 8-way partials: contention /8
  for (int q = threadIdx.x; q < 512; q += 256) {
    float sv = ls[q] + ls[512 + q] + ls[1024 + q] + ls[1536 + q];
    atomicAdd(&bp[q], sv);
  }
}

// ---------------- final: BN(pbn2)+ReLU folded, 256 -> 3 projection ----------------
__global__ __launch_bounds__(256) void final_kernel(const f16* __restrict__ hq,
                                                    const float* __restrict__ sums,
                                                    const float* __restrict__ gamma,
                                                    const float* __restrict__ beta,
                                                    const float* __restrict__ W,
                                                    const float* __restrict__ b,
                                                    float* __restrict__ out3) {
  int wave = threadIdx.x >> 6, lane = threadIdx.x & 63;
  int n = blockIdx.x * 4 + wave;
  if (n >= Nn) return;
  int ch = lane * 4;
  float su_[4] = {0.f, 0.f, 0.f, 0.f}, sq_[4] = {0.f, 0.f, 0.f, 0.f};
#pragma unroll
  for (int p = 0; p < 8; ++p) {
    float4 su = *(const float4*)(sums + p * 512 + ch);
    float4 sq = *(const float4*)(sums + p * 512 + 256 + ch);
    su_[0] += su.x; su_[1] += su.y; su_[2] += su.z; su_[3] += su.w;
    sq_[0] += sq.x; sq_[1] += sq.y; sq_[2] += sq.z; sq_[3] += sq.w;
  }
  float4 g4 = *(const float4*)(gamma + ch);
  float4 b4 = *(const float4*)(beta + ch);
  float g_[4] = {g4.x, g4.y, g4.z, g4.w};
  float bb_[4] = {b4.x, b4.y, b4.z, b4.w};
  f16x4 h4 = *(const f16x4*)(hq + (size_t)n * 256 + ch);
  float s0 = 0.f, s1 = 0.f, s2 = 0.f;
#pragma unroll
  for (int c = 0; c < 4; ++c) {
    float mu = su_[c] * (1.f / Nn);
    float var = fmaxf(sq_[c] * (1.f / Nn) - mu * mu, 0.f);
    float is = rsqrtf(var + 1e-5f) * g_[c];
    float y = fmaxf(((float)h4[c] - mu) * is + bb_[c], 0.f);
    const float* w = W + (ch + c) * 3;
    s0 += y * w[0]; s1 += y * w[1]; s2 += y * w[2];
  }
  for (int off = 1; off < 64; off <<= 1) {
    s0 += __shfl_xor(s0, off);
    s1 += __shfl_xor(s1, off);
    s2 += __shfl_xor(s2, off);
  }
  if (lane == 0) {
    out3[n * 3 + 0] = s0 + b[0];
    out3[n * 3 + 1] = s1 + b[1];
    out3[n * 3 + 2] = s2 + b[2];
  }
}

extern "C" void kernel_launch(void* const* d_in, const int* in_sizes, int n_in,
                              void* d_out, int out_size, void* d_ws, size_t ws_size,
                              hipStream_t stream) {
  const float* x         = (const float*)d_in[0];
  const float* edge_attr = (const float*)d_in[1];
  const int*   eidx      = (const int*)d_in[2];
  const float* lift_W    = (const float*)d_in[3];
  const float* lift_b    = (const float*)d_in[4];
  const float* Wl        = (const float*)d_in[5];
  const float* bl        = (const float*)d_in[6];
  const float* Wr        = (const float*)d_in[7];
  const float* br        = (const float*)d_in[8];
  const float* We        = (const float*)d_in[9];
  const float* att       = (const float*)d_in[10];
  const float* conv_b    = (const float*)d_in[11];
  const float* bn_g      = (const float*)d_in[12];
  const float* bn_b      = (const float*)d_in[13];
  const float* p1_W      = (const float*)d_in[14];
  const float* p1_b      = (const float*)d_in[15];
  const float* pbn1_g    = (const float*)d_in[16];
  const float* pbn1_b    = (const float*)d_in[17];
  const float* p2_W      = (const float*)d_in[18];
  const float* p2_b      = (const float*)d_in[19];
  const float* pbn2_g    = (const float*)d_in[20];
  const float* pbn2_b    = (const float*)d_in[21];
  const float* p3_W      = (const float*)d_in[22];
  const float* p3_b      = (const float*)d_in[23];
  const int* srcI = eidx;
  const int* dstI = eidx + Ee;

  char* wp = (char*)d_ws;
  auto carve = [&](size_t bytes) -> void* {
    void* p = (void*)wp;
    wp += (bytes + 255) & ~(size_t)255;
    return p;
  };
  // zero region: cstats(32) + bnsA(7 sets x 8 partials x 512) + deg(Nn)
  char*  zr     = (char*)carve((size_t)(32 + 7 * 4096 + Nn) * 4);
  float* cstats = (float*)zr;
  float* bnsA   = (float*)(zr + 32 * 4);
  int*   deg    = (int*)(zr + (32 + 7 * 4096) * 4);
  float* eap    = (float*)carve((size_t)Ee * 12 * sizeof(float));
  f16*   h16    = (f16*)carve((size_t)Nn * 256 * sizeof(f16));
  f16*   w16t   = (f16*)carve((size_t)786432 * sizeof(f16));
  float* biascat= (float*)carve((size_t)2560 * sizeof(float));
  f16*   xlb    = (f16*)carve((size_t)Nn * 256 * sizeof(f16));
  f16*   xrb    = (f16*)carve((size_t)Nn * 256 * sizeof(f16));
  f16*   outb16 = (f16*)carve((size_t)Nn * 256 * sizeof(f16));
  int*   rowptr = (int*)carve((size_t)(Nn + 1) * sizeof(int));
  int*   cursor = (int*)carve((size_t)Nn * sizeof(int));
  int*   srcp   = (int*)carve((size_t)Ee * sizeof(int));

  hipMemsetAsync(zr, 0, (size_t)(32 + 7 * 4096 + Nn) * 4, stream);

  prologue_kernel<<<10882, 256, 0, stream>>>(edge_attr, dstI, cstats, deg,
                                             x, lift_W, lift_b, h16,
                                             Wl, Wr, p1_W, p2_W, bl, br, w16t, biascat);
  scan_kernel<<<1, 1024, 0, stream>>>(deg, rowptr, cursor);
  fill_eaperm_kernel<<<(Ee + 255) / 256, 256, 0, stream>>>(edge_attr, cstats, srcI, dstI,
                                                           cursor, srcp, eap);

  const int MB = (Nn + 63) / 64;  // 157
  for (int t = 0; t < Tt; ++t) {
    const f16* Ain = (t == 0) ? h16 : outb16;
    const float* sums = (t == 0) ? nullptr : bnsA + (size_t)(t - 1) * 4096;
    int act = (t == 0) ? -1 : 0;
    gemm16_kernel<<<dim3(8, MB), 256, 0, stream>>>(Ain, w16t + (size_t)t * 131072,
                                                   biascat + t * 512, sums,
                                                   bn_g + (t > 0 ? (t - 1) * 256 : 0),
                                                   bn_b + (t > 0 ? (t - 1) * 256 : 0),
                                                   act, xlb, Nn, 256, nullptr, xrb);
    gat_fused<<<2500, 256, 0, stream>>>(xlb, xrb, eap, srcp, rowptr,
                                        We + t * 9 * 256, att + t * 256,
                                        conv_b + t * 256, outb16,
                                        bnsA + (size_t)t * 4096);
  }
  // projection head: BN folds in A-staging; output stats fused in gemm epilogue
  f16* pA = xlb;  // Nn*256, reused
  f16* pB = xrb;  // Nn*256, reused
  gemm16_kernel<<<dim3(4, MB), 256, 0, stream>>>(outb16, w16t + 655360, p1_b,
                                                 bnsA + 4 * 4096, bn_g + 4 * 256, bn_b + 4 * 256,
                                                 0, pA, Nn, 256, bnsA + 5 * 4096, nullptr);
  gemm16_kernel<<<dim3(4, MB), 256, 0, stream>>>(pA, w16t + 720896, p2_b,
                                                 bnsA + 5 * 4096, pbn1_g, pbn1_b,
                                                 1, pB, Nn, 256, bnsA + 6 * 4096, nullptr);
  final_kernel<<<2500, 256, 0, stream>>>(pB, bnsA + 6 * 4096, pbn2_g, pbn2_b, p3_W, p3_b,
                                         (float*)d_out);
}

// Round 9
// 556.981 us; speedup vs baseline: 1.1249x; 1.0430x over previous
//
#include <hip/hip_runtime.h>

#define Nn 10000
#define Ee 160000
#define HID 256
#define EDIM 9
#define INDIM 10
#define Tt 5

typedef _Float16 f16;
typedef _Float16 f16x8 __attribute__((ext_vector_type(8)));
typedef _Float16 f16x4 __attribute__((ext_vector_type(4)));
typedef float f32x4 __attribute__((ext_vector_type(4)));

// ---- mega-prologue: independent jobs on disjoint block ranges ----
// blocks [0,64):      edge-attr column stats
// blocks [64,689):    degree histogram
// blocks [689,3189):  lift h = relu(x @ lift_W + b) -> f16, 4 nodes/block
//                     (was 1 node/block x 10000 blocks: dispatch-rate bound)
// blocks [3189,3381): weight fp32->f16 transpose, LDS-tiled 64x64 coalesced
// block  3381:        bias concat
__global__ __launch_bounds__(256) void prologue_kernel(
    const float* __restrict__ edge_attr, const int* __restrict__ dst,
    float* __restrict__ cs, int* __restrict__ deg,
    const float* __restrict__ x, const float* __restrict__ lift_W,
    const float* __restrict__ lift_b, f16* __restrict__ hq,
    const float* __restrict__ Wl, const float* __restrict__ Wr,
    const float* __restrict__ p1, const float* __restrict__ p2,
    const float* __restrict__ bl, const float* __restrict__ br,
    f16* __restrict__ wt, float* __restrict__ biascat) {
  __shared__ float tile[64][65];
  const int blk = blockIdx.x;
  if (blk < 64) {
    float s[9], s2[9];
#pragma unroll
    for (int k = 0; k < 9; ++k) { s[k] = 0.f; s2[k] = 0.f; }
    for (int i = blk * 256 + threadIdx.x; i < Ee; i += 64 * 256) {
#pragma unroll
      for (int k = 0; k < 9; ++k) {
        float v = edge_attr[i * 9 + k];
        s[k] += v; s2[k] += v * v;
      }
    }
#pragma unroll
    for (int k = 0; k < 9; ++k) {
      for (int off = 1; off < 64; off <<= 1) {
        s[k] += __shfl_xor(s[k], off);
        s2[k] += __shfl_xor(s2[k], off);
      }
    }
    if ((threadIdx.x & 63) == 0) {
#pragma unroll
      for (int k = 0; k < 9; ++k) {
        atomicAdd(&cs[k], s[k]);
        atomicAdd(&cs[16 + k], s2[k]);
      }
    }
  } else if (blk < 689) {
    int e = (blk - 64) * 256 + threadIdx.x;
    if (e < Ee) atomicAdd(&deg[dst[e]], 1);
  } else if (blk < 3189) {
    // lift: 4 nodes/block; thread = (node l = tid>>6, 4 channels at (tid&63)*4)
    __shared__ float xs[4][INDIM];
    int n0 = (blk - 689) * 4;
    if (threadIdx.x < 40) {
      int l = threadIdx.x / INDIM, k = threadIdx.x % INDIM;
      xs[l][k] = x[(n0 + l) * INDIM + k];
    }
    __syncthreads();
    int l = threadIdx.x >> 6, chb = (threadIdx.x & 63) * 4;
    float4 b4 = *(const float4*)(lift_b + chb);
    float s0 = b4.x, s1 = b4.y, s2 = b4.z, s3 = b4.w;
#pragma unroll
    for (int k = 0; k < INDIM; ++k) {
      float4 w4 = *(const float4*)(lift_W + k * 256 + chb);
      float xv = xs[l][k];
      s0 += xv * w4.x; s1 += xv * w4.y; s2 += xv * w4.z; s3 += xv * w4.w;
    }
    f16x4 o;
    o[0] = (f16)fmaxf(s0, 0.f); o[1] = (f16)fmaxf(s1, 0.f);
    o[2] = (f16)fmaxf(s2, 0.f); o[3] = (f16)fmaxf(s3, 0.f);
    *(f16x4*)(hq + (size_t)(n0 + l) * 256 + chb) = o;
  } else if (blk < 3381) {
    // coalesced transpose: src fp32 [256 k][256 n] -> wt f16 [n][k]
    int b = blk - 3189;             // 0..191
    int m = b >> 4, t4 = b & 15;    // matrix, 64x64 tile
    int ti = t4 >> 2, tj = t4 & 3;  // out-row (n) tile, k tile
    const float* src; size_t dbase;
    if (m < 10) {
      int t = m >> 1;
      src = (m & 1) ? (Wr + t * 65536) : (Wl + t * 65536);
      dbase = (size_t)t * 131072 + ((m & 1) ? (size_t)65536 : 0);
    } else if (m == 10) { src = p1; dbase = 655360; }
    else { src = p2; dbase = 720896; }
#pragma unroll
    for (int p = 0; p < 16; ++p) {
      int idx = threadIdx.x + p * 256;  // 0..4095
      int kl = idx >> 6, nl = idx & 63;
      tile[kl][nl] = src[(size_t)(tj * 64 + kl) * 256 + ti * 64 + nl];
    }
    __syncthreads();
#pragma unroll
    for (int p = 0; p < 16; ++p) {
      int idx = threadIdx.x + p * 256;
      int nl = idx >> 6, kl = idx & 63;
      wt[dbase + (size_t)(ti * 64 + nl) * 256 + tj * 64 + kl] = (f16)tile[kl][nl];
    }
  } else {
    for (int flat = threadIdx.x; flat < 2560; flat += 256) {
      int t = flat >> 9, c = flat & 511;
      biascat[flat] = (c < 256) ? bl[t * 256 + c] : br[t * 256 + c - 256];
    }
  }
}

// ---------------- CSR rowptr scan (single block) ----------------
__global__ __launch_bounds__(1024) void scan_kernel(const int* __restrict__ deg,
                                                    int* __restrict__ rowptr,
                                                    int* __restrict__ cursor) {
  __shared__ int part[1024];
  int tid = threadIdx.x;
  const int CH = (Nn + 1023) / 1024;
  int start = tid * CH;
  int s = 0;
  for (int i = 0; i < CH; ++i) { int idx = start + i; if (idx < Nn) s += deg[idx]; }
  part[tid] = s;
  __syncthreads();
  for (int off = 1; off < 1024; off <<= 1) {
    int v = part[tid];
    int w = (tid >= off) ? part[tid - off] : 0;
    __syncthreads();
    part[tid] = v + w;
    __syncthreads();
  }
  int run = part[tid] - s;  // exclusive prefix
  for (int i = 0; i < CH; ++i) {
    int idx = start + i;
    if (idx < Nn) { rowptr[idx] = run; cursor[idx] = run; run += deg[idx]; }
  }
  if (tid == 0) rowptr[Nn] = Ee;
}

// ---- fused CSR fill + src permute + edge-attr normalize (f32, stride 12) ----
__global__ __launch_bounds__(256) void fill_eaperm_kernel(const float* __restrict__ edge_attr,
                                                          const float* __restrict__ cs,
                                                          const int* __restrict__ srcIn,
                                                          const int* __restrict__ dstIn,
                                                          int* __restrict__ cursor,
                                                          int* __restrict__ srcp,
                                                          float* __restrict__ eap) {
  int e = blockIdx.x * 256 + threadIdx.x;
  if (e >= Ee) return;
  int pos = atomicAdd(&cursor[dstIn[e]], 1);
  srcp[pos] = srcIn[e];
  const float* a = edge_attr + e * 9;
  float o[12];
#pragma unroll
  for (int k = 0; k < 9; ++k) {
    float mu = cs[k] * (1.f / Ee);
    float var = fmaxf(cs[16 + k] * (1.f / Ee) - mu * mu, 0.f);
    o[k] = (a[k] - mu) / (sqrtf(var) + 1e-8f);
  }
  o[9] = o[10] = o[11] = 0.f;
  float4 v0 = {o[0], o[1], o[2], o[3]};
  float4 v1 = {o[4], o[5], o[6], o[7]};
  float4 v2 = {o[8], o[9], o[10], o[11]};
  *(float4*)(eap + (size_t)pos * 12 + 0) = v0;
  *(float4*)(eap + (size_t)pos * 12 + 4) = v1;
  *(float4*)(eap + (size_t)pos * 12 + 8) = v2;
}

// ------------- fp16 MFMA GEMM: A staged in LDS, B streamed from L2 -------------
// out2 != nullptr: n-tiles with n0>=256 are routed to out2 at column n0-256.
__global__ __launch_bounds__(256) void gemm16_kernel(const f16* __restrict__ A,
                                                     const f16* __restrict__ BT,
                                                     const float* __restrict__ bias,
                                                     const float* __restrict__ sums,
                                                     const float* __restrict__ gamma,
                                                     const float* __restrict__ beta,
                                                     int act,
                                                     f16* __restrict__ out,
                                                     int M, int OS,
                                                     float* __restrict__ statsout,
                                                     f16* __restrict__ out2) {
  __shared__ __align__(16) f16 As[64][264];
  const int tid = threadIdx.x;
  const int wave = tid >> 6, lane = tid & 63;
  const int l15 = lane & 15, quad = lane >> 4;
  const int m0 = blockIdx.y * 64, n0 = blockIdx.x * 64;
  const int wm = (wave >> 1) * 32, wn = (wave & 1) * 32;
  const int colbase = (tid & 31) * 8;
  float sA[8], tA[8];
  if (act >= 0) {
#pragma unroll
    for (int c4 = 0; c4 < 2; ++c4) {
      float su_[4] = {0.f, 0.f, 0.f, 0.f}, sq_[4] = {0.f, 0.f, 0.f, 0.f};
#pragma unroll
      for (int p = 0; p < 8; ++p) {
        float4 su = *(const float4*)(sums + p * 512 + colbase + c4 * 4);
        float4 sq = *(const float4*)(sums + p * 512 + 256 + colbase + c4 * 4);
        su_[0] += su.x; su_[1] += su.y; su_[2] += su.z; su_[3] += su.w;
        sq_[0] += sq.x; sq_[1] += sq.y; sq_[2] += sq.z; sq_[3] += sq.w;
      }
      float4 g4 = *(const float4*)(gamma + colbase + c4 * 4);
      float4 b4 = *(const float4*)(beta + colbase + c4 * 4);
      float g_[4] = {g4.x, g4.y, g4.z, g4.w};
      float b_[4] = {b4.x, b4.y, b4.z, b4.w};
#pragma unroll
      for (int c = 0; c < 4; ++c) {
        float mu = su_[c] * (1.f / Nn);
        float var = fmaxf(sq_[c] * (1.f / Nn) - mu * mu, 0.f);
        float is = rsqrtf(var + 1e-5f) * g_[c];
        sA[c4 * 4 + c] = is;
        tA[c4 * 4 + c] = b_[c] - mu * is;
      }
    }
  }
  // stage A panel (64x256) only: 8 x 16B chunks per thread
#pragma unroll
  for (int i = 0; i < 8; ++i) {
    int c = tid + 256 * i;
    int row = c >> 5, col = (c & 31) * 8;
    f16x8 av = {};
    int gm = m0 + row;
    if (gm < M) av = *(const f16x8*)(A + (size_t)gm * 256 + col);
    if (act >= 0) {
#pragma unroll
      for (int e = 0; e < 8; ++e) {
        float y = (float)av[e] * sA[e] + tA[e];
        if (act == 0) y = y > 0.f ? y : (__expf(y) - 1.f);
        else y = fmaxf(y, 0.f);
        av[e] = (f16)y;
      }
    }
    *(f16x8*)(&As[row][col]) = av;
  }
  __syncthreads();
  const f16* pb0 = BT + (size_t)(n0 + wn + l15) * 256 + quad * 8;
  const f16* pb1 = BT + (size_t)(n0 + wn + 16 + l15) * 256 + quad * 8;
  f32x4 zero4 = {0.f, 0.f, 0.f, 0.f};
  f32x4 acc[2][2] = {{zero4, zero4}, {zero4, zero4}};
#pragma unroll
  for (int kk = 0; kk < 256; kk += 32) {
    f16x8 a0 = *(const f16x8*)(&As[wm + l15][kk + quad * 8]);
    f16x8 a1 = *(const f16x8*)(&As[wm + 16 + l15][kk + quad * 8]);
    f16x8 b0 = *(const f16x8*)(pb0 + kk);
    f16x8 b1 = *(const f16x8*)(pb1 + kk);
    acc[0][0] = __builtin_amdgcn_mfma_f32_16x16x32_f16(a0, b0, acc[0][0], 0, 0, 0);
    acc[0][1] = __builtin_amdgcn_mfma_f32_16x16x32_f16(a0, b1, acc[0][1], 0, 0, 0);
    acc[1][0] = __builtin_amdgcn_mfma_f32_16x16x32_f16(a1, b0, acc[1][0], 0, 0, 0);
    acc[1][1] = __builtin_amdgcn_mfma_f32_16x16x32_f16(a1, b1, acc[1][1], 0, 0, 0);
  }
  // epilogue: bias add, fp16 via LDS transpose; optional register-space stats
  __syncthreads();
  f16* Cs = (f16*)&As[0][0];  // 64 x 72 tile (reuses As)
  float st_s[2] = {0.f, 0.f}, st_q[2] = {0.f, 0.f};
#pragma unroll
  for (int ni = 0; ni < 2; ++ni) {
    int nl = wn + ni * 16 + l15;
    float bv = bias[n0 + nl];
#pragma unroll
    for (int mi = 0; mi < 2; ++mi)
#pragma unroll
      for (int r = 0; r < 4; ++r) {
        f16 hv = (f16)(acc[mi][ni][r] + bv);
        Cs[(wm + mi * 16 + quad * 4 + r) * 72 + nl] = hv;
        if (statsout) {
          int gm = m0 + wm + mi * 16 + quad * 4 + r;
          float xv = (gm < M) ? (float)hv : 0.f;
          st_s[ni] += xv;
          st_q[ni] += xv * xv;
        }
      }
  }
  if (statsout) {
    float* bp = statsout + (blockIdx.y & 7) * 512;
#pragma unroll
    for (int ni = 0; ni < 2; ++ni) {
      float s = st_s[ni], q = st_q[ni];
      s += __shfl_xor(s, 16); q += __shfl_xor(q, 16);
      s += __shfl_xor(s, 32); q += __shfl_xor(q, 32);
      if (quad == 0) {
        int col = n0 + wn + ni * 16 + l15;
        atomicAdd(&bp[col], s);
        atomicAdd(&bp[256 + col], q);
      }
    }
  }
  __syncthreads();
  {
    int row = tid >> 2, c4 = (tid & 3) * 16;
    int gm = m0 + row;
    f16* op = out; int nc = n0;
    if (out2 && n0 >= 256) { op = out2; nc = n0 - 256; }
    if (gm < M) {
      f16x8 v0 = *(const f16x8*)(&Cs[row * 72 + c4]);
      f16x8 v1 = *(const f16x8*)(&Cs[row * 72 + c4 + 8]);
      *(f16x8*)(op + (size_t)gm * OS + nc + c4) = v0;
      *(f16x8*)(op + (size_t)gm * OS + nc + c4 + 8) = v1;
    }
  }
}

// ---- Fused GATv2 + BN stats: wave/node, batch-4 (verified R6 body, reverted
// from R7 shfl-prefetch and R8 nontemporal-eap, both of which regressed) ----
__global__ __launch_bounds__(256) void gat_fused(const f16* __restrict__ xlb,
                                                 const f16* __restrict__ xrb,
                                                 const float* __restrict__ eap,
                                                 const int* __restrict__ srcp,
                                                 const int* __restrict__ rowptr,
                                                 const float* __restrict__ We_t,
                                                 const float* __restrict__ att_t,
                                                 const float* __restrict__ cb_t,
                                                 f16* __restrict__ outb,
                                                 float* __restrict__ bns) {
  __shared__ float ls[2048];  // [wave][sum 256 | sumsq 256]
  int wave = threadIdx.x >> 6, lane = threadIdx.x & 63;
  int i = blockIdx.x * 4 + wave;  // 2500 * 4 == Nn exactly
  int ch = lane * 4;  // lane owns flat channels [ch, ch+4); head = lane>>3
  float we[9][4];
#pragma unroll
  for (int k = 0; k < 9; ++k) {
    float4 w4 = *(const float4*)(We_t + k * 256 + ch);
    we[k][0] = w4.x; we[k][1] = w4.y; we[k][2] = w4.z; we[k][3] = w4.w;
  }
  float4 a4 = *(const float4*)(att_t + ch);
  float att[4] = {a4.x, a4.y, a4.z, a4.w};
  f16x4 xr4 = *(const f16x4*)(xrb + (size_t)i * 256 + ch);
  float xri[4] = {(float)xr4[0], (float)xr4[1], (float)xr4[2], (float)xr4[3]};
  float acc[4] = {0.f, 0.f, 0.f, 0.f};
  float d = 0.f;
  int r0 = rowptr[i], r1 = rowptr[i + 1];
  for (int base = r0; base < r1; base += 4) {
    int cnt = r1 - base;  // >= 1
    int ib[4];
#pragma unroll
    for (int b = 0; b < 4; ++b) ib[b] = base + (b < cnt ? b : cnt - 1);
    int js[4];
#pragma unroll
    for (int b = 0; b < 4; ++b) js[b] = srcp[ib[b]];
    float xlv[4][4];
#pragma unroll
    for (int b = 0; b < 4; ++b) {
      f16x4 v4 = *(const f16x4*)(xlb + (size_t)js[b] * 256 + ch);
      xlv[b][0] = (float)v4[0]; xlv[b][1] = (float)v4[1];
      xlv[b][2] = (float)v4[2]; xlv[b][3] = (float)v4[3];
    }
    float sp[4];
#pragma unroll
    for (int b = 0; b < 4; ++b) {
      const float* ep = eap + (size_t)ib[b] * 12;
      float4 e0 = *(const float4*)ep;
      float4 e1 = *(const float4*)(ep + 4);
      float e8 = ep[8];
      float s = 0.f;
#pragma unroll
      for (int c = 0; c < 4; ++c) {
        float v = xlv[b][c] + xri[c];
        v += e0.x * we[0][c] + e0.y * we[1][c] + e0.z * we[2][c] + e0.w * we[3][c];
        v += e1.x * we[4][c] + e1.y * we[5][c] + e1.z * we[6][c] + e1.w * we[7][c];
        v += e8 * we[8][c];
        v = v > 0.f ? v : 0.2f * v;  // leaky_relu 0.2
        s += att[c] * v;
      }
      sp[b] = s;
    }
#pragma unroll
    for (int b = 0; b < 4; ++b) {
      sp[b] += __shfl_xor(sp[b], 1);
      sp[b] += __shfl_xor(sp[b], 2);
      sp[b] += __shfl_xor(sp[b], 4);
    }
#pragma unroll
    for (int b = 0; b < 4; ++b) {
      float z = (b < cnt) ? __expf(fminf(sp[b], 75.f)) : 0.f;
      d += z;
#pragma unroll
      for (int c = 0; c < 4; ++c) acc[c] += z * xlv[b][c];
    }
  }
  float inv = 1.f / (d + 1e-16f);  // empty node -> bias only (matches ref)
  float4 cb4 = *(const float4*)(cb_t + ch);
  f16x4 o;
  o[0] = (f16)(acc[0] * inv + cb4.x);
  o[1] = (f16)(acc[1] * inv + cb4.y);
  o[2] = (f16)(acc[2] * inv + cb4.z);
  o[3] = (f16)(acc[3] * inv + cb4.w);
  *(f16x4*)(outb + (size_t)i * 256 + ch) = o;
  // fused BN stats on the f16-rounded output
#pragma unroll
  for (int c = 0; c < 4; ++c) {
    float xv = (float)o[c];
    ls[wave * 512 + ch + c] = xv;
    ls[wave * 512 + 256 + ch + c] = xv * xv;
  }
  __syncthreads();
  float* bp = bns + (blockIdx.x & 7) * 512;  // 8-way partials: contention /8
  for (int q = threadIdx.x; q < 512; q += 256) {
    float sv = ls[q] + ls[512 + q] + ls[1024 + q] + ls[1536 + q];
    atomicAdd(&bp[q], sv);
  }
}

// ---------------- final: BN(pbn2)+ReLU folded, 256 -> 3 projection ----------------
__global__ __launch_bounds__(256) void final_kernel(const f16* __restrict__ hq,
                                                    const float* __restrict__ sums,
                                                    const float* __restrict__ gamma,
                                                    const float* __restrict__ beta,
                                                    const float* __restrict__ W,
                                                    const float* __restrict__ b,
                                                    float* __restrict__ out3) {
  int wave = threadIdx.x >> 6, lane = threadIdx.x & 63;
  int n = blockIdx.x * 4 + wave;
  if (n >= Nn) return;
  int ch = lane * 4;
  float su_[4] = {0.f, 0.f, 0.f, 0.f}, sq_[4] = {0.f, 0.f, 0.f, 0.f};
#pragma unroll
  for (int p = 0; p < 8; ++p) {
    float4 su = *(const float4*)(sums + p * 512 + ch);
    float4 sq = *(const float4*)(sums + p * 512 + 256 + ch);
    su_[0] += su.x; su_[1] += su.y; su_[2] += su.z; su_[3] += su.w;
    sq_[0] += sq.x; sq_[1] += sq.y; sq_[2] += sq.z; sq_[3] += sq.w;
  }
  float4 g4 = *(const float4*)(gamma + ch);
  float4 b4 = *(const float4*)(beta + ch);
  float g_[4] = {g4.x, g4.y, g4.z, g4.w};
  float bb_[4] = {b4.x, b4.y, b4.z, b4.w};
  f16x4 h4 = *(const f16x4*)(hq + (size_t)n * 256 + ch);
  float s0 = 0.f, s1 = 0.f, s2 = 0.f;
#pragma unroll
  for (int c = 0; c < 4; ++c) {
    float mu = su_[c] * (1.f / Nn);
    float var = fmaxf(sq_[c] * (1.f / Nn) - mu * mu, 0.f);
    float is = rsqrtf(var + 1e-5f) * g_[c];
    float y = fmaxf(((float)h4[c] - mu) * is + bb_[c], 0.f);
    const float* w = W + (ch + c) * 3;
    s0 += y * w[0]; s1 += y * w[1]; s2 += y * w[2];
  }
  for (int off = 1; off < 64; off <<= 1) {
    s0 += __shfl_xor(s0, off);
    s1 += __shfl_xor(s1, off);
    s2 += __shfl_xor(s2, off);
  }
  if (lane == 0) {
    out3[n * 3 + 0] = s0 + b[0];
    out3[n * 3 + 1] = s1 + b[1];
    out3[n * 3 + 2] = s2 + b[2];
  }
}

extern "C" void kernel_launch(void* const* d_in, const int* in_sizes, int n_in,
                              void* d_out, int out_size, void* d_ws, size_t ws_size,
                              hipStream_t stream) {
  const float* x         = (const float*)d_in[0];
  const float* edge_attr = (const float*)d_in[1];
  const int*   eidx      = (const int*)d_in[2];
  const float* lift_W    = (const float*)d_in[3];
  const float* lift_b    = (const float*)d_in[4];
  const float* Wl        = (const float*)d_in[5];
  const float* bl        = (const float*)d_in[6];
  const float* Wr        = (const float*)d_in[7];
  const float* br        = (const float*)d_in[8];
  const float* We        = (const float*)d_in[9];
  const float* att       = (const float*)d_in[10];
  const float* conv_b    = (const float*)d_in[11];
  const float* bn_g      = (const float*)d_in[12];
  const float* bn_b      = (const float*)d_in[13];
  const float* p1_W      = (const float*)d_in[14];
  const float* p1_b      = (const float*)d_in[15];
  const float* pbn1_g    = (const float*)d_in[16];
  const float* pbn1_b    = (const float*)d_in[17];
  const float* p2_W      = (const float*)d_in[18];
  const float* p2_b      = (const float*)d_in[19];
  const float* pbn2_g    = (const float*)d_in[20];
  const float* pbn2_b    = (const float*)d_in[21];
  const float* p3_W      = (const float*)d_in[22];
  const float* p3_b      = (const float*)d_in[23];
  const int* srcI = eidx;
  const int* dstI = eidx + Ee;

  char* wp = (char*)d_ws;
  auto carve = [&](size_t bytes) -> void* {
    void* p = (void*)wp;
    wp += (bytes + 255) & ~(size_t)255;
    return p;
  };
  // zero region: cstats(32) + bnsA(7 sets x 8 partials x 512) + deg(Nn)
  char*  zr     = (char*)carve((size_t)(32 + 7 * 4096 + Nn) * 4);
  float* cstats = (float*)zr;
  float* bnsA   = (float*)(zr + 32 * 4);
  int*   deg    = (int*)(zr + (32 + 7 * 4096) * 4);
  float* eap    = (float*)carve((size_t)Ee * 12 * sizeof(float));
  f16*   h16    = (f16*)carve((size_t)Nn * 256 * sizeof(f16));
  f16*   w16t   = (f16*)carve((size_t)786432 * sizeof(f16));
  float* biascat= (float*)carve((size_t)2560 * sizeof(float));
  f16*   xlb    = (f16*)carve((size_t)Nn * 256 * sizeof(f16));
  f16*   xrb    = (f16*)carve((size_t)Nn * 256 * sizeof(f16));
  f16*   outb16 = (f16*)carve((size_t)Nn * 256 * sizeof(f16));
  int*   rowptr = (int*)carve((size_t)(Nn + 1) * sizeof(int));
  int*   cursor = (int*)carve((size_t)Nn * sizeof(int));
  int*   srcp   = (int*)carve((size_t)Ee * sizeof(int));

  hipMemsetAsync(zr, 0, (size_t)(32 + 7 * 4096 + Nn) * 4, stream);

  prologue_kernel<<<3382, 256, 0, stream>>>(edge_attr, dstI, cstats, deg,
                                            x, lift_W, lift_b, h16,
                                            Wl, Wr, p1_W, p2_W, bl, br, w16t, biascat);
  scan_kernel<<<1, 1024, 0, stream>>>(deg, rowptr, cursor);
  fill_eaperm_kernel<<<(Ee + 255) / 256, 256, 0, stream>>>(edge_attr, cstats, srcI, dstI,
                                                           cursor, srcp, eap);

  const int MB = (Nn + 63) / 64;  // 157
  for (int t = 0; t < Tt; ++t) {
    const f16* Ain = (t == 0) ? h16 : outb16;
    const float* sums = (t == 0) ? nullptr : bnsA + (size_t)(t - 1) * 4096;
    int act = (t == 0) ? -1 : 0;
    gemm16_kernel<<<dim3(8, MB), 256, 0, stream>>>(Ain, w16t + (size_t)t * 131072,
                                                   biascat + t * 512, sums,
                                                   bn_g + (t > 0 ? (t - 1) * 256 : 0),
                                                   bn_b + (t > 0 ? (t - 1) * 256 : 0),
                                                   act, xlb, Nn, 256, nullptr, xrb);
    gat_fused<<<2500, 256, 0, stream>>>(xlb, xrb, eap, srcp, rowptr,
                                        We + t * 9 * 256, att + t * 256,
                                        conv_b + t * 256, outb16,
                                        bnsA + (size_t)t * 4096);
  }
  // projection head: BN folds in A-staging; output stats fused in gemm epilogue
  f16* pA = xlb;  // Nn*256, reused
  f16* pB = xrb;  // Nn*256, reused
  gemm16_kernel<<<dim3(4, MB), 256, 0, stream>>>(outb16, w16t + 655360, p1_b,
                                                 bnsA + 4 * 4096, bn_g + 4 * 256, bn_b + 4 * 256,
                                                 0, pA, Nn, 256, bnsA + 5 * 4096, nullptr);
  gemm16_kernel<<<dim3(4, MB), 256, 0, stream>>>(pA, w16t + 720896, p2_b,
                                                 bnsA + 5 * 4096, pbn1_g, pbn1_b,
                                                 1, pB, Nn, 256, bnsA + 6 * 4096, nullptr);
  final_kernel<<<2500, 256, 0, stream>>>(pB, bnsA + 6 * 4096, pbn2_g, pbn2_b, p3_W, p3_b,
                                         (float*)d_out);
}